// Round 7
// baseline (449.743 us; speedup 1.0000x reference)
//
#include <hip/hip_runtime.h>
#include <cmath>

#define EPSF 1e-5f

typedef __bf16 bfx8 __attribute__((ext_vector_type(8)));
typedef float  f32x4 __attribute__((ext_vector_type(4)));

__device__ __forceinline__ float4 ld4(const float* p){ return *(const float4*)p; }
__device__ __forceinline__ unsigned f2bf(float f){
    unsigned u = __builtin_bit_cast(unsigned, f);
    return (u + 0x7FFFu + ((u >> 16) & 1u)) >> 16;
}
__device__ __forceinline__ float bf2f(unsigned u){
    return __builtin_bit_cast(float, u << 16);
}
__device__ __forceinline__ bfx8 lds_ld(const char* p){ return *(const bfx8*)p; }
__device__ __forceinline__ bfx8 gbl_ld(const unsigned short* p){ return *(const bfx8*)p; }
__device__ __forceinline__ unsigned short bf16u(float f){ return (unsigned short)f2bf(f); }

// ---------------------------------------------------------------------------
// all weights -> bf16 transposed, one dispatch. segs 0..4: 128x128, seg 5: 256x64
// ---------------------------------------------------------------------------
__global__ __launch_bounds__(256)
void wconv_all(const float* __restrict__ s0, const float* __restrict__ s1,
               const float* __restrict__ s2, const float* __restrict__ s3,
               const float* __restrict__ s4, const float* __restrict__ s5,
               unsigned short* __restrict__ WT)
{
    int seg = blockIdx.x >> 6;
    int i = (blockIdx.x & 63)*256 + threadIdx.x;
    if (seg < 5) {
        const float* s = seg==0?s0: seg==1?s1: seg==2?s2: seg==3?s3: s4;
        int c = i >> 7, k = i & 127;
        WT[seg*16384 + i] = bf16u(s[(size_t)k*128 + c]);
    } else {
        int c = i >> 8, k = i & 255;
        WT[5*16384 + i] = bf16u(s5[(size_t)k*64 + c]);
    }
}

// ---------------------------------------------------------------------------
// fused front end, per 64-row tile (all row-local):
//   H  = relu(LN(x@tfc + tfcb))          [H on-chip: regs + 16KB LDS]
//   G  = relu(BN(x@gfc + gfcb)) -> Gf (f32) + Gb (bf16)  [direct stores]
//   V  = H@wv + wvb;  XT = relu(LN(0.5V + 0.5H)) -> XTb
//   [attention term ~1e-8, dropped: q,k normalized by GLOBAL Frobenius norms]
// B-operands read DIRECTLY from global (L1/L2-resident 32KB weights) — no LDS
// staging, no per-wave duplication. LDS: Ar 16K (x tile) | Hst 16K (H tile).
// 2 syncthreads total.
// ---------------------------------------------------------------------------
__global__ __launch_bounds__(256)
void fused_front(const float* __restrict__ x,
                 const unsigned short* __restrict__ wt_tfc,
                 const unsigned short* __restrict__ wt_wv,
                 const unsigned short* __restrict__ wt_gfc,
                 const float* __restrict__ tfcb, const float* __restrict__ ln0g,
                 const float* __restrict__ ln0b, const float* __restrict__ wvb,
                 const float* __restrict__ ln1g, const float* __restrict__ ln1b,
                 const float* __restrict__ gfcb, const float* __restrict__ bn0g,
                 const float* __restrict__ bn0b, const float* __restrict__ bn0m,
                 const float* __restrict__ bn0v,
                 unsigned short* __restrict__ XTb, float* __restrict__ Gf,
                 unsigned short* __restrict__ Gb, int nrows)
{
    __shared__ __align__(16) char lds[32768];
    char* Ar  = lds;            // 16KB: x tile bf16 swz
    char* Hst = lds + 16384;    // 16KB: H tile bf16 swz
    const int tid  = threadIdx.x;
    const int row0 = blockIdx.x * 64;
    const int w  = tid >> 6, ln = tid & 63, lr = ln & 15, lg = ln >> 4;
    const int ksw = (lr & 7) << 4;

    // --- stage x tile (f32 -> bf16, swizzled) ---
    #pragma unroll
    for (int i = 0; i < 4; ++i) {
        int c  = tid + i*256, r = c >> 4, k0 = (c & 15)*8;
        uint4 v4 = make_uint4(0,0,0,0);
        if (row0 + r < nrows) {
            float4 f0 = ld4(&x[(size_t)(row0+r)*128 + k0]);
            float4 f1 = ld4(&x[(size_t)(row0+r)*128 + k0 + 4]);
            v4.x = f2bf(f0.x) | (f2bf(f0.y) << 16);
            v4.y = f2bf(f0.z) | (f2bf(f0.w) << 16);
            v4.z = f2bf(f1.x) | (f2bf(f1.y) << 16);
            v4.w = f2bf(f1.z) | (f2bf(f1.w) << 16);
        }
        *(uint4*)&Ar[r*256 + ((k0*2) ^ ((r&7)<<4))] = v4;
    }
    __syncthreads();

    const char* Ab = &Ar[(w*16 + lr)*256];
    f32x4 acc[8];
    float h[8][4];

    // --- GEMM1: x @ tfc (B from global) ---
    #pragma unroll
    for (int nf = 0; nf < 8; ++nf) acc[nf] = (f32x4){0.f,0.f,0.f,0.f};
    #pragma unroll
    for (int ks = 0; ks < 4; ++ks) {
        int kb = (ks*64 + lg*16);
        bfx8 a = lds_ld(Ab + (kb ^ ksw));
        bfx8 bf[8];
        #pragma unroll
        for (int nf = 0; nf < 8; ++nf)
            bf[nf] = gbl_ld(&wt_tfc[(size_t)(nf*16 + lr)*128 + ks*32 + lg*8]);
        #pragma unroll
        for (int nf = 0; nf < 8; ++nf)
            acc[nf] = __builtin_amdgcn_mfma_f32_16x16x32_bf16(a, bf[nf], acc[nf], 0, 0, 0);
    }
    // --- LN0 + relu -> h regs ---
    {
        float gl[8], bl[8];
        #pragma unroll
        for (int nf = 0; nf < 8; ++nf) {
            int c = nf*16 + lr;
            gl[nf] = ln0g[c]; bl[nf] = ln0b[c];
            float bb = tfcb[c];
            #pragma unroll
            for (int i = 0; i < 4; ++i) h[nf][i] = acc[nf][i] + bb;
        }
        #pragma unroll
        for (int i = 0; i < 4; ++i) {
            float s = 0.f, s2 = 0.f;
            #pragma unroll
            for (int nf = 0; nf < 8; ++nf) { s += h[nf][i]; s2 += h[nf][i]*h[nf][i]; }
            #pragma unroll
            for (int m = 1; m < 16; m <<= 1) { s += __shfl_xor(s, m); s2 += __shfl_xor(s2, m); }
            float mean = s * (1.f/128.f);
            float inv  = rsqrtf(s2 * (1.f/128.f) - mean*mean + EPSF);
            #pragma unroll
            for (int nf = 0; nf < 8; ++nf)
                h[nf][i] = fmaxf((h[nf][i]-mean)*inv*gl[nf] + bl[nf], 0.f);
        }
    }
    // --- GEMM3: x @ gfc ; G = relu(BN) -> direct stores ---
    #pragma unroll
    for (int nf = 0; nf < 8; ++nf) acc[nf] = (f32x4){0.f,0.f,0.f,0.f};
    #pragma unroll
    for (int ks = 0; ks < 4; ++ks) {
        int kb = (ks*64 + lg*16);
        bfx8 a = lds_ld(Ab + (kb ^ ksw));
        bfx8 bf[8];
        #pragma unroll
        for (int nf = 0; nf < 8; ++nf)
            bf[nf] = gbl_ld(&wt_gfc[(size_t)(nf*16 + lr)*128 + ks*32 + lg*8]);
        #pragma unroll
        for (int nf = 0; nf < 8; ++nf)
            acc[nf] = __builtin_amdgcn_mfma_f32_16x16x32_bf16(a, bf[nf], acc[nf], 0, 0, 0);
    }
    #pragma unroll
    for (int nf = 0; nf < 8; ++nf) {
        int c = nf*16 + lr;
        float sc = bn0g[c] * rsqrtf(bn0v[c] + EPSF);
        float sh = bn0b[c] - bn0m[c]*sc;
        float bb = gfcb[c];
        #pragma unroll
        for (int i = 0; i < 4; ++i) {
            float v = fmaxf((acc[nf][i] + bb)*sc + sh, 0.f);
            int r = row0 + w*16 + lg*4 + i;
            if (r < nrows) {
                Gf[(size_t)r*128 + c] = v;
                Gb[(size_t)r*128 + c] = bf16u(v);
            }
        }
    }
    // --- write H (bf16) into Hst, swizzled, scalar ---
    #pragma unroll
    for (int nf = 0; nf < 8; ++nf) {
        int c = nf*16 + lr;
        #pragma unroll
        for (int i = 0; i < 4; ++i) {
            int r = w*16 + lg*4 + i;
            *(unsigned short*)&Hst[(r*256 + c*2) ^ ((r&7)<<4)] = bf16u(h[nf][i]);
        }
    }
    __syncthreads();
    // --- GEMM2: H @ wv ; XT = relu(LN(0.5V + 0.5H)) -> direct bf16 stores ---
    const char* Hb = &Hst[(w*16 + lr)*256];
    #pragma unroll
    for (int nf = 0; nf < 8; ++nf) acc[nf] = (f32x4){0.f,0.f,0.f,0.f};
    #pragma unroll
    for (int ks = 0; ks < 4; ++ks) {
        int kb = (ks*64 + lg*16);
        bfx8 a = lds_ld(Hb + (kb ^ ksw));
        bfx8 bf[8];
        #pragma unroll
        for (int nf = 0; nf < 8; ++nf)
            bf[nf] = gbl_ld(&wt_wv[(size_t)(nf*16 + lr)*128 + ks*32 + lg*8]);
        #pragma unroll
        for (int nf = 0; nf < 8; ++nf)
            acc[nf] = __builtin_amdgcn_mfma_f32_16x16x32_bf16(a, bf[nf], acc[nf], 0, 0, 0);
    }
    {
        float gl[8], bl[8];
        #pragma unroll
        for (int nf = 0; nf < 8; ++nf) {
            int c = nf*16 + lr;
            gl[nf] = ln1g[c]; bl[nf] = ln1b[c];
            float bb = wvb[c];
            #pragma unroll
            for (int i = 0; i < 4; ++i)
                h[nf][i] = 0.5f*(acc[nf][i] + bb) + 0.5f*h[nf][i];
        }
        #pragma unroll
        for (int i = 0; i < 4; ++i) {
            float s = 0.f, s2 = 0.f;
            #pragma unroll
            for (int nf = 0; nf < 8; ++nf) { s += h[nf][i]; s2 += h[nf][i]*h[nf][i]; }
            #pragma unroll
            for (int m = 1; m < 16; m <<= 1) { s += __shfl_xor(s, m); s2 += __shfl_xor(s2, m); }
            float mean = s * (1.f/128.f);
            float inv  = rsqrtf(s2 * (1.f/128.f) - mean*mean + EPSF);
            #pragma unroll
            for (int nf = 0; nf < 8; ++nf) {
                float v = fmaxf((h[nf][i]-mean)*inv*gl[nf] + bl[nf], 0.f);
                int r = row0 + w*16 + lg*4 + i;
                if (r < nrows)
                    XTb[(size_t)r*128 + nf*16 + lr] = bf16u(v);
            }
        }
    }
}

// ---------------------------------------------------------------------------
// MFMA GEMM (GNN layers): C = BN_relu( A@W + bias ) + resid; A bf16 in global,
// B from global (L1/L2-hot), direct epilogue stores. LDS: 16KB A-tile only.
// ---------------------------------------------------------------------------
template<bool OUTF32, bool OUTBF16>
__global__ __launch_bounds__(256)
void mgemm(const unsigned short* __restrict__ Ab16, const unsigned short* __restrict__ WT,
           const float* __restrict__ bias, float* __restrict__ Cf,
           unsigned short* __restrict__ Cb, int nrows,
           const float* __restrict__ p0, const float* __restrict__ p1,
           const float* __restrict__ p2, const float* __restrict__ p3,
           const float* __restrict__ resid)
{
    __shared__ __align__(16) char lds[16384];
    const int tid  = threadIdx.x;
    const int row0 = blockIdx.x * 64;
    const int w  = tid >> 6, ln = tid & 63, lr = ln & 15, lg = ln >> 4;
    const int ksw = (lr & 7) << 4;

    #pragma unroll
    for (int i = 0; i < 4; ++i) {
        int c  = tid + i*256, r = c >> 4, k0 = (c & 15)*8;
        uint4 v = make_uint4(0,0,0,0);
        if (row0 + r < nrows)
            v = *(const uint4*)&Ab16[(size_t)(row0+r)*128 + k0];
        *(uint4*)&lds[r*256 + ((k0*2) ^ ((r&7)<<4))] = v;
    }
    __syncthreads();

    const char* Ab = &lds[(w*16 + lr)*256];
    f32x4 acc[8];
    #pragma unroll
    for (int nf = 0; nf < 8; ++nf) acc[nf] = (f32x4){0.f,0.f,0.f,0.f};
    #pragma unroll
    for (int ks = 0; ks < 4; ++ks) {
        int kb = (ks*64 + lg*16);
        bfx8 a = lds_ld(Ab + (kb ^ ksw));
        bfx8 bf[8];
        #pragma unroll
        for (int nf = 0; nf < 8; ++nf)
            bf[nf] = gbl_ld(&WT[(size_t)(nf*16 + lr)*128 + ks*32 + lg*8]);
        #pragma unroll
        for (int nf = 0; nf < 8; ++nf)
            acc[nf] = __builtin_amdgcn_mfma_f32_16x16x32_bf16(a, bf[nf], acc[nf], 0, 0, 0);
    }

    #pragma unroll
    for (int nf = 0; nf < 8; ++nf) {
        int c = nf*16 + lr;
        float sc = p0[c] * rsqrtf(p3[c] + EPSF);
        float sh = p1[c] - p2[c]*sc;
        float bb = bias[c];
        #pragma unroll
        for (int i = 0; i < 4; ++i) {
            int r = row0 + w*16 + lg*4 + i;
            if (r < nrows) {
                float v = fmaxf((acc[nf][i] + bb)*sc + sh, 0.f) + resid[(size_t)r*128 + c];
                if constexpr (OUTF32)  Cf[(size_t)r*128 + c] = v;
                if constexpr (OUTBF16) Cb[(size_t)r*128 + c] = bf16u(v);
            }
        }
    }
}

// ---------------------------------------------------------------------------
// out GEMM: out = tanh( [XTb | G2b](bf16, K=256) @ WT(64x256 bf16) + B )
// A in 32KB LDS, B from global, direct f32 stores.
// ---------------------------------------------------------------------------
__global__ __launch_bounds__(256)
void out_mfma(const unsigned short* __restrict__ XTb,
              const unsigned short* __restrict__ G2b,
              const unsigned short* __restrict__ WT,
              const float* __restrict__ B, float* __restrict__ out, int nrows)
{
    __shared__ __align__(16) char lds[32768];
    const int tid  = threadIdx.x;
    const int row0 = blockIdx.x * 64;
    const int w  = tid >> 6, ln = tid & 63, lr = ln & 15, lg = ln >> 4;
    const int ksw = (lr & 7) << 4;

    #pragma unroll
    for (int i = 0; i < 8; ++i) {
        int c  = tid + i*256, r = c >> 5, k0 = (c & 31)*8;
        uint4 v = make_uint4(0,0,0,0);
        if (row0 + r < nrows) {
            const unsigned short* src = (k0 < 128)
                ? &XTb[(size_t)(row0+r)*128 + k0]
                : &G2b[(size_t)(row0+r)*128 + (k0-128)];
            v = *(const uint4*)src;
        }
        *(uint4*)&lds[r*512 + ((k0*2) ^ ((r&7)<<4))] = v;
    }
    __syncthreads();

    const char* Ab = &lds[(w*16 + lr)*512];
    f32x4 acc[4];
    #pragma unroll
    for (int nf = 0; nf < 4; ++nf) acc[nf] = (f32x4){0.f,0.f,0.f,0.f};
    #pragma unroll
    for (int ks = 0; ks < 8; ++ks) {
        int kb = (ks*64 + lg*16);
        bfx8 a = lds_ld(Ab + (kb ^ ksw));
        bfx8 bf[4];
        #pragma unroll
        for (int nf = 0; nf < 4; ++nf)
            bf[nf] = gbl_ld(&WT[(size_t)(nf*16 + lr)*256 + ks*32 + lg*8]);
        #pragma unroll
        for (int nf = 0; nf < 4; ++nf)
            acc[nf] = __builtin_amdgcn_mfma_f32_16x16x32_bf16(a, bf[nf], acc[nf], 0, 0, 0);
    }
    #pragma unroll
    for (int nf = 0; nf < 4; ++nf) {
        float bb = B[nf*16 + lr];
        #pragma unroll
        for (int i = 0; i < 4; ++i) {
            int r = row0 + w*16 + lg*4 + i;
            if (r < nrows)
                out[(size_t)r*64 + nf*16 + lr] = tanhf(acc[nf][i] + bb);
        }
    }
}

// ---------------------------------------------------------------------------
// CSR build: histogram -> multi-block scan -> fill (packed row|val)
// ---------------------------------------------------------------------------
__global__ __launch_bounds__(256)
void edge_hist(const int* __restrict__ col, const int* __restrict__ et,
               int* __restrict__ cnt, int n, int ne)
{
    int e = blockIdx.x*256 + threadIdx.x;
    if (e >= ne) return;
    atomicAdd(&cnt[et[e]*n + col[e]], 1);
}

__global__ __launch_bounds__(1024)
void scan_block(const int* __restrict__ cnt, int* __restrict__ off,
                int* __restrict__ bsum, int n)
{
    __shared__ int s[1024];
    const int t = threadIdx.x;
    const int i = blockIdx.x*1024 + t;
    int v = (i < n) ? cnt[i] : 0;
    s[t] = v;
    __syncthreads();
    #pragma unroll
    for (int d = 1; d < 1024; d <<= 1) {
        int u = (t >= d) ? s[t-d] : 0;
        __syncthreads();
        s[t] += u;
        __syncthreads();
    }
    if (i < n) off[i] = s[t] - v;
    if (t == 1023) bsum[blockIdx.x] = s[1023];
}

__global__ __launch_bounds__(256)
void scan_bsums(int* __restrict__ bsum, int nb)
{
    __shared__ int s[256];
    const int t = threadIdx.x;
    int v = (t < nb) ? bsum[t] : 0;
    s[t] = v;
    __syncthreads();
    #pragma unroll
    for (int d = 1; d < 256; d <<= 1) {
        int u = (t >= d) ? s[t-d] : 0;
        __syncthreads();
        s[t] += u;
        __syncthreads();
    }
    if (t < nb) bsum[t] = s[t] - v;
}

__global__ __launch_bounds__(1024)
void scan_add(int* __restrict__ off, const int* __restrict__ bsum, int n)
{
    int i = blockIdx.x*1024 + threadIdx.x;
    if (i < n) off[i] += bsum[blockIdx.x];
}

__global__ __launch_bounds__(256)
void edge_fill(const int* __restrict__ row_idx, const int* __restrict__ col_idx,
               const int* __restrict__ et, const float* __restrict__ ew,
               const int* __restrict__ cnt, const int* __restrict__ off,
               int* __restrict__ cursor, uint2* __restrict__ ePack, int n, int ne)
{
    int e = blockIdx.x*256 + threadIdx.x;
    if (e >= ne) return;
    int t = et[e], c = col_idx[e], r = row_idx[e];
    int ic = t*n + c;
    int pos = atomicAdd(&cursor[ic], 1);
    int idx = off[ic] + pos;
    int p = cnt[ic] * cnt[t*n + r];
    float val = (p > 0) ? ew[e] * rsqrtf((float)p) : 0.f;
    ePack[idx] = make_uint2((unsigned)r, __builtin_bit_cast(unsigned, val));
}

// ---------------------------------------------------------------------------
// CSR gather (bf16 in, bf16 out): one wave per node, lane = 2 feature cols
// ---------------------------------------------------------------------------
__global__ __launch_bounds__(256)
void hetero_gather(const unsigned short* __restrict__ Gb,
                   const uint2* __restrict__ ePack,
                   const int* __restrict__ cnt, const int* __restrict__ off,
                   unsigned short* __restrict__ AGGb, int n)
{
    int node = blockIdx.x*4 + (threadIdx.x >> 6);
    if (node >= n) return;
    const int lane = threadIdx.x & 63;
    const int base = off[node];
    const int m = cnt[node];
    float ax = 0.f, ay = 0.f;
    int i = 0;
    for (; i + 1 < m; i += 2) {
        uint2 p0 = ePack[base+i];
        uint2 p1 = ePack[base+i+1];
        unsigned g0 = *(const unsigned*)&Gb[(size_t)p0.x*128 + lane*2];
        unsigned g1 = *(const unsigned*)&Gb[(size_t)p1.x*128 + lane*2];
        float v0 = __builtin_bit_cast(float, p0.y);
        float v1 = __builtin_bit_cast(float, p1.y);
        ax += v0*bf2f(g0 & 0xffff) + v1*bf2f(g1 & 0xffff);
        ay += v0*bf2f(g0 >> 16)    + v1*bf2f(g1 >> 16);
    }
    if (i < m) {
        uint2 p0 = ePack[base+i];
        unsigned g0 = *(const unsigned*)&Gb[(size_t)p0.x*128 + lane*2];
        float v0 = __builtin_bit_cast(float, p0.y);
        ax += v0*bf2f(g0 & 0xffff);
        ay += v0*bf2f(g0 >> 16);
    }
    unsigned pk = f2bf(ax) | (f2bf(ay) << 16);
    *(unsigned*)&AGGb[(size_t)node*128 + lane*2] = pk;
}

extern "C" void kernel_launch(void* const* d_in, const int* in_sizes, int n_in,
                              void* d_out, int out_size, void* d_ws, size_t ws_size,
                              hipStream_t stream)
{
    const float* x      = (const float*)d_in[0];
    const float* ew     = (const float*)d_in[1];
    const float* t_fc_w = (const float*)d_in[2];
    const float* t_fc_b = (const float*)d_in[3];
    const float* ln0g   = (const float*)d_in[4];
    const float* ln0b   = (const float*)d_in[5];
    const float* wvw    = (const float*)d_in[10];
    const float* wvb    = (const float*)d_in[11];
    const float* ln1g   = (const float*)d_in[12];
    const float* ln1b   = (const float*)d_in[13];
    const float* gfcw   = (const float*)d_in[14];
    const float* gfcb   = (const float*)d_in[15];
    const float* bn0g   = (const float*)d_in[16];
    const float* bn0b   = (const float*)d_in[17];
    const float* bn0m   = (const float*)d_in[18];
    const float* bn0v   = (const float*)d_in[19];
    const float* gw1    = (const float*)d_in[20];
    const float* gb1    = (const float*)d_in[21];
    const float* bn1g   = (const float*)d_in[22];
    const float* bn1b   = (const float*)d_in[23];
    const float* bn1m   = (const float*)d_in[24];
    const float* bn1v   = (const float*)d_in[25];
    const float* gw2    = (const float*)d_in[26];
    const float* gb2    = (const float*)d_in[27];
    const float* bn2g   = (const float*)d_in[28];
    const float* bn2b   = (const float*)d_in[29];
    const float* bn2m   = (const float*)d_in[30];
    const float* bn2v   = (const float*)d_in[31];
    const float* outw   = (const float*)d_in[32];
    const float* outb   = (const float*)d_in[33];
    const int*   ei     = (const int*)d_in[34];
    const int*   et     = (const int*)d_in[35];

    const int N = 100000, E = 800000;
    const size_t NF = (size_t)N*128;
    float* F1 = (float*)d_ws;                         // G1 (resid for g2)
    float* F2 = F1 + NF;                              // G  (resid for g1)
    unsigned short* B1 = (unsigned short*)(F2 + NF);  // AGG0 / AGG1
    unsigned short* B2 = B1 + NF;                     // G2b
    unsigned short* B3 = B2 + NF;                     // Gb -> G1b
    unsigned short* B4 = B3 + NF;                     // XTb
    unsigned short* WT = B4 + NF;
    unsigned short* wt_tfc = WT;
    unsigned short* wt_wv  = WT + 16384;
    unsigned short* wt_gfc = WT + 2*16384;
    unsigned short* wt_g1  = WT + 3*16384;
    unsigned short* wt_g2  = WT + 4*16384;
    unsigned short* wt_out = WT + 5*16384;            // 64x256
    int*   cnt    = (int*)(WT + 6*16384);             // [2N]
    int*   cursor = cnt + 2*N;                        // [2N]
    int*   off    = cursor + 2*N;                     // [2N]
    uint2* ePack  = (uint2*)(off + 2*N);              // [E]
    int*   bsum   = (int*)(ePack + E);                // [256]

    dim3 blk(256);
    const int nb64 = (N + 63) / 64;
    const int* row_idx = ei;
    const int* col_idx = ei + E;
    const int nscan = 2*N;
    const int nsb = (nscan + 1023) / 1024;

    // --- CSR build ---
    hipMemsetAsync(cnt, 0, 4*(size_t)N*sizeof(int), stream);
    edge_hist<<<(E + 255)/256, blk, 0, stream>>>(col_idx, et, cnt, N, E);
    scan_block<<<nsb, 1024, 0, stream>>>(cnt, off, bsum, nscan);
    scan_bsums<<<1, 256, 0, stream>>>(bsum, nsb);
    scan_add<<<nsb, 1024, 0, stream>>>(off, bsum, nscan);
    edge_fill<<<(E + 255)/256, blk, 0, stream>>>(row_idx, col_idx, et, ew,
                                                 cnt, off, cursor, ePack, N, E);

    // --- weights -> bf16 transposed (single dispatch) ---
    wconv_all<<<384, blk, 0, stream>>>(t_fc_w, wvw, gfcw, gw1, gw2, outw, WT);

    // --- fused front end: XTb, G(f32), Gb ---
    fused_front<<<nb64, blk, 0, stream>>>(x, wt_tfc, wt_wv, wt_gfc,
        t_fc_b, ln0g, ln0b, wvb, ln1g, ln1b,
        gfcb, bn0g, bn0b, bn0m, bn0v, B4, F2, B3, N);

    // --- GNN chain ---
    hetero_gather<<<(N + 3)/4, blk, 0, stream>>>(B3, ePack, cnt,     off,     B1, N);
    mgemm<true,true><<<nb64, blk, 0, stream>>>(B1, wt_g1, gb1, F1, B3, N,
                                               bn1g, bn1b, bn1m, bn1v, F2);
    hetero_gather<<<(N + 3)/4, blk, 0, stream>>>(B3, ePack, cnt + N, off + N, B1, N);
    mgemm<false,true><<<nb64, blk, 0, stream>>>(B1, wt_g2, gb2, nullptr, B2, N,
                                                bn2g, bn2b, bn2m, bn2v, F1);

    out_mfma<<<nb64, blk, 0, stream>>>(B4, B2, wt_out, outb, (float*)d_out, N);
}

// Round 8
// 383.438 us; speedup vs baseline: 1.1729x; 1.1729x over previous
//
#include <hip/hip_runtime.h>
#include <cmath>

#define EPSF 1e-5f

typedef __bf16 bfx8 __attribute__((ext_vector_type(8)));
typedef float  f32x4 __attribute__((ext_vector_type(4)));

__device__ __forceinline__ float4 ld4(const float* p){ return *(const float4*)p; }
__device__ __forceinline__ unsigned f2bf(float f){
    unsigned u = __builtin_bit_cast(unsigned, f);
    return (u + 0x7FFFu + ((u >> 16) & 1u)) >> 16;
}
__device__ __forceinline__ float bf2f(unsigned u){
    return __builtin_bit_cast(float, u << 16);
}
__device__ __forceinline__ bfx8 lds_ld(const char* p){ return *(const bfx8*)p; }
__device__ __forceinline__ unsigned short bf16u(float f){ return (unsigned short)f2bf(f); }

// ---------------------------------------------------------------------------
// weights -> bf16 FRAGMENT layout in global:
//   seg<5 (128x128): chunk=(nf*4+ks)*64+ln, elem j = W[k][c],
//       c=nf*16+(ln&15), k=ks*32+(ln>>4)*8+j     (2048 chunks/seg)
//   seg5  (256x64):  chunk=(nf*8+ks)*64+ln, same formula with 64 cols.
// LDS staging then = pure linear copy; wave MFMA reads are 64 consecutive
// 16B chunks -> zero extra bank conflicts.
// ---------------------------------------------------------------------------
__global__ __launch_bounds__(256)
void wconv_all(const float* __restrict__ s0, const float* __restrict__ s1,
               const float* __restrict__ s2, const float* __restrict__ s3,
               const float* __restrict__ s4, const float* __restrict__ s5,
               unsigned short* __restrict__ WT)
{
    int gid   = blockIdx.x*256 + threadIdx.x;   // chunk id, 12288 total
    int seg   = gid >> 11;
    int chunk = gid & 2047;
    int ln    = chunk & 63;
    unsigned short tmp[8];
    if (seg < 5) {
        const float* s = seg==0?s0: seg==1?s1: seg==2?s2: seg==3?s3: s4;
        int nf = chunk >> 8, ks = (chunk >> 6) & 3;
        int c  = nf*16 + (ln & 15);
        int k0 = ks*32 + (ln >> 4)*8;
        #pragma unroll
        for (int j = 0; j < 8; ++j) tmp[j] = bf16u(s[(size_t)(k0+j)*128 + c]);
        *(uint4*)&WT[seg*16384 + chunk*8] = *(uint4*)tmp;
    } else {
        int nf = chunk >> 9, ks = (chunk >> 6) & 7;
        int c  = nf*16 + (ln & 15);
        int k0 = ks*32 + (ln >> 4)*8;
        #pragma unroll
        for (int j = 0; j < 8; ++j) tmp[j] = bf16u(s5[(size_t)(k0+j)*64 + c]);
        *(uint4*)&WT[5*16384 + chunk*8] = *(uint4*)tmp;
    }
}

// ---------------------------------------------------------------------------
// fused front end (5 barriers, no LDS C-stage):
//   H  = relu(LN(x@tfc+b))  [regs]; G = relu(BN(x@gfc+b)) -> Gf,Gb (direct)
//   V = H@wv+b; XT = relu(LN(.5V+.5H)) -> XTb (direct)
//   [attention term ~1e-8, dropped: q,k normalized by GLOBAL Frobenius norm]
// LDS 48KB: Ar 16K (x frags, later H frags) | Wr 32K (B frags) -> 3 blk/CU
// ---------------------------------------------------------------------------
__global__ __launch_bounds__(256)
void fused_front(const float* __restrict__ x,
                 const unsigned short* __restrict__ wt_tfc,
                 const unsigned short* __restrict__ wt_wv,
                 const unsigned short* __restrict__ wt_gfc,
                 const float* __restrict__ tfcb, const float* __restrict__ ln0g,
                 const float* __restrict__ ln0b, const float* __restrict__ wvb,
                 const float* __restrict__ ln1g, const float* __restrict__ ln1b,
                 const float* __restrict__ gfcb, const float* __restrict__ bn0g,
                 const float* __restrict__ bn0b, const float* __restrict__ bn0m,
                 const float* __restrict__ bn0v,
                 unsigned short* __restrict__ XTb, float* __restrict__ Gf,
                 unsigned short* __restrict__ Gb, int nrows)
{
    __shared__ __align__(16) char lds[49152];
    char* Ar = lds;            // 16KB: A fragments
    char* Wr = lds + 16384;    // 32KB: B fragments
    const int tid  = threadIdx.x;
    const int row0 = blockIdx.x * 64;
    const int w  = tid >> 6, ln = tid & 63, lr = ln & 15, lg = ln >> 4;
    const int lnoff = ln*16;

    // --- stage x -> Ar fragment layout (f32 -> bf16) ---
    #pragma unroll
    for (int i = 0; i < 4; ++i) {
        int c  = tid + i*256;                 // chunk 0..1023
        int l2 = c & 63, ks = (c>>6)&3, g = c>>8;
        int r  = g*16 + (l2 & 15);
        int k0 = ks*32 + (l2 >> 4)*8;
        uint4 v4 = make_uint4(0,0,0,0);
        if (row0 + r < nrows) {
            float4 f0 = ld4(&x[(size_t)(row0+r)*128 + k0]);
            float4 f1 = ld4(&x[(size_t)(row0+r)*128 + k0 + 4]);
            v4.x = f2bf(f0.x) | (f2bf(f0.y) << 16);
            v4.y = f2bf(f0.z) | (f2bf(f0.w) << 16);
            v4.z = f2bf(f1.x) | (f2bf(f1.y) << 16);
            v4.w = f2bf(f1.z) | (f2bf(f1.w) << 16);
        }
        *(uint4*)&Ar[c*16] = v4;
    }
    // --- stage tfc (linear frag copy) ---
    #pragma unroll
    for (int i = 0; i < 8; ++i) {
        int c = tid + i*256;
        *(uint4*)&Wr[c*16] = *(const uint4*)&wt_tfc[c*8];
    }
    __syncthreads();                                      // (1)

    f32x4 acc[8];
    float h[8][4];

    // --- GEMM1: x @ tfc ---
    #pragma unroll
    for (int nf = 0; nf < 8; ++nf) acc[nf] = (f32x4){0.f,0.f,0.f,0.f};
    #pragma unroll
    for (int ks = 0; ks < 4; ++ks) {
        bfx8 a = lds_ld(&Ar[w*4096 + ks*1024 + lnoff]);
        #pragma unroll
        for (int nf = 0; nf < 8; ++nf) {
            bfx8 b = lds_ld(&Wr[(nf*4+ks)*1024 + lnoff]);
            acc[nf] = __builtin_amdgcn_mfma_f32_16x16x32_bf16(a, b, acc[nf], 0, 0, 0);
        }
    }
    // --- LN0 + relu -> h regs ---
    {
        float gl[8], bl[8];
        #pragma unroll
        for (int nf = 0; nf < 8; ++nf) {
            int c = nf*16 + lr;
            gl[nf] = ln0g[c]; bl[nf] = ln0b[c];
            float bb = tfcb[c];
            #pragma unroll
            for (int i = 0; i < 4; ++i) h[nf][i] = acc[nf][i] + bb;
        }
        #pragma unroll
        for (int i = 0; i < 4; ++i) {
            float s = 0.f, s2 = 0.f;
            #pragma unroll
            for (int nf = 0; nf < 8; ++nf) { s += h[nf][i]; s2 += h[nf][i]*h[nf][i]; }
            #pragma unroll
            for (int m = 1; m < 16; m <<= 1) { s += __shfl_xor(s, m); s2 += __shfl_xor(s2, m); }
            float mean = s * (1.f/128.f);
            float inv  = rsqrtf(s2 * (1.f/128.f) - mean*mean + EPSF);
            #pragma unroll
            for (int nf = 0; nf < 8; ++nf)
                h[nf][i] = fmaxf((h[nf][i]-mean)*inv*gl[nf] + bl[nf], 0.f);
        }
    }
    __syncthreads();                                      // (2) Wr reads done
    // --- stage gfc ---
    #pragma unroll
    for (int i = 0; i < 8; ++i) {
        int c = tid + i*256;
        *(uint4*)&Wr[c*16] = *(const uint4*)&wt_gfc[c*8];
    }
    __syncthreads();                                      // (3)
    // --- GEMM3: x @ gfc ; G = relu(BN) -> direct stores ---
    #pragma unroll
    for (int nf = 0; nf < 8; ++nf) acc[nf] = (f32x4){0.f,0.f,0.f,0.f};
    #pragma unroll
    for (int ks = 0; ks < 4; ++ks) {
        bfx8 a = lds_ld(&Ar[w*4096 + ks*1024 + lnoff]);
        #pragma unroll
        for (int nf = 0; nf < 8; ++nf) {
            bfx8 b = lds_ld(&Wr[(nf*4+ks)*1024 + lnoff]);
            acc[nf] = __builtin_amdgcn_mfma_f32_16x16x32_bf16(a, b, acc[nf], 0, 0, 0);
        }
    }
    #pragma unroll
    for (int nf = 0; nf < 8; ++nf) {
        int c = nf*16 + lr;
        float sc = bn0g[c] * rsqrtf(bn0v[c] + EPSF);
        float sh = bn0b[c] - bn0m[c]*sc;
        float bb = gfcb[c];
        #pragma unroll
        for (int i = 0; i < 4; ++i) {
            int r = row0 + w*16 + lg*4 + i;
            if (r < nrows) {
                float v = fmaxf((acc[nf][i] + bb)*sc + sh, 0.f);
                Gf[(size_t)r*128 + c] = v;
                Gb[(size_t)r*128 + c] = bf16u(v);
            }
        }
    }
    __syncthreads();                                      // (4) Ar+Wr reads done
    // --- write H -> Ar fragment layout (x dead); stage wv ---
    #pragma unroll
    for (int nf = 0; nf < 8; ++nf) {
        int c2  = nf*16 + lr;
        int ksA = c2 >> 5;
        int lgA = (c2 >> 3) & 3;
        int jb  = (c2 & 7) * 2;
        #pragma unroll
        for (int i = 0; i < 4; ++i) {
            int rl = lg*4 + i;
            *(unsigned short*)&Ar[((w*4 + ksA)*64 + lgA*16 + rl)*16 + jb] = bf16u(h[nf][i]);
        }
    }
    #pragma unroll
    for (int i = 0; i < 8; ++i) {
        int c = tid + i*256;
        *(uint4*)&Wr[c*16] = *(const uint4*)&wt_wv[c*8];
    }
    __syncthreads();                                      // (5)
    // --- GEMM2: H @ wv ; XT = relu(LN(.5V+.5H)) -> direct bf16 stores ---
    #pragma unroll
    for (int nf = 0; nf < 8; ++nf) acc[nf] = (f32x4){0.f,0.f,0.f,0.f};
    #pragma unroll
    for (int ks = 0; ks < 4; ++ks) {
        bfx8 a = lds_ld(&Ar[w*4096 + ks*1024 + lnoff]);
        #pragma unroll
        for (int nf = 0; nf < 8; ++nf) {
            bfx8 b = lds_ld(&Wr[(nf*4+ks)*1024 + lnoff]);
            acc[nf] = __builtin_amdgcn_mfma_f32_16x16x32_bf16(a, b, acc[nf], 0, 0, 0);
        }
    }
    {
        float gl[8], bl[8];
        #pragma unroll
        for (int nf = 0; nf < 8; ++nf) {
            int c = nf*16 + lr;
            gl[nf] = ln1g[c]; bl[nf] = ln1b[c];
            float bb = wvb[c];
            #pragma unroll
            for (int i = 0; i < 4; ++i)
                h[nf][i] = 0.5f*(acc[nf][i] + bb) + 0.5f*h[nf][i];
        }
        #pragma unroll
        for (int i = 0; i < 4; ++i) {
            float s = 0.f, s2 = 0.f;
            #pragma unroll
            for (int nf = 0; nf < 8; ++nf) { s += h[nf][i]; s2 += h[nf][i]*h[nf][i]; }
            #pragma unroll
            for (int m = 1; m < 16; m <<= 1) { s += __shfl_xor(s, m); s2 += __shfl_xor(s2, m); }
            float mean = s * (1.f/128.f);
            float inv  = rsqrtf(s2 * (1.f/128.f) - mean*mean + EPSF);
            #pragma unroll
            for (int nf = 0; nf < 8; ++nf) {
                int r = row0 + w*16 + lg*4 + i;
                if (r < nrows) {
                    float v = fmaxf((h[nf][i]-mean)*inv*gl[nf] + bl[nf], 0.f);
                    XTb[(size_t)r*128 + nf*16 + lr] = bf16u(v);
                }
            }
        }
    }
}

// ---------------------------------------------------------------------------
// MFMA GEMM (GNN layers): C = BN_relu(A@W + bias) + resid; fragment LDS,
// single barrier, direct stores.
// ---------------------------------------------------------------------------
template<bool OUTF32, bool OUTBF16>
__global__ __launch_bounds__(256)
void mgemm(const unsigned short* __restrict__ Ab16, const unsigned short* __restrict__ WTf,
           const float* __restrict__ bias, float* __restrict__ Cf,
           unsigned short* __restrict__ Cb, int nrows,
           const float* __restrict__ p0, const float* __restrict__ p1,
           const float* __restrict__ p2, const float* __restrict__ p3,
           const float* __restrict__ resid)
{
    __shared__ __align__(16) char lds[49152];
    char* Ar = lds;
    char* Wr = lds + 16384;
    const int tid  = threadIdx.x;
    const int row0 = blockIdx.x * 64;
    const int w  = tid >> 6, ln = tid & 63, lr = ln & 15, lg = ln >> 4;
    const int lnoff = ln*16;

    #pragma unroll
    for (int i = 0; i < 4; ++i) {
        int c  = tid + i*256;
        int l2 = c & 63, ks = (c>>6)&3, g = c>>8;
        int r  = g*16 + (l2 & 15);
        int k0 = ks*32 + (l2 >> 4)*8;
        uint4 v = make_uint4(0,0,0,0);
        if (row0 + r < nrows)
            v = *(const uint4*)&Ab16[(size_t)(row0+r)*128 + k0];
        *(uint4*)&Ar[c*16] = v;
    }
    #pragma unroll
    for (int i = 0; i < 8; ++i) {
        int c = tid + i*256;
        *(uint4*)&Wr[c*16] = *(const uint4*)&WTf[c*8];
    }
    __syncthreads();

    f32x4 acc[8];
    #pragma unroll
    for (int nf = 0; nf < 8; ++nf) acc[nf] = (f32x4){0.f,0.f,0.f,0.f};
    #pragma unroll
    for (int ks = 0; ks < 4; ++ks) {
        bfx8 a = lds_ld(&Ar[w*4096 + ks*1024 + lnoff]);
        #pragma unroll
        for (int nf = 0; nf < 8; ++nf) {
            bfx8 b = lds_ld(&Wr[(nf*4+ks)*1024 + lnoff]);
            acc[nf] = __builtin_amdgcn_mfma_f32_16x16x32_bf16(a, b, acc[nf], 0, 0, 0);
        }
    }

    #pragma unroll
    for (int nf = 0; nf < 8; ++nf) {
        int c = nf*16 + lr;
        float sc = p0[c] * rsqrtf(p3[c] + EPSF);
        float sh = p1[c] - p2[c]*sc;
        float bb = bias[c];
        #pragma unroll
        for (int i = 0; i < 4; ++i) {
            int r = row0 + w*16 + lg*4 + i;
            if (r < nrows) {
                float v = fmaxf((acc[nf][i] + bb)*sc + sh, 0.f) + resid[(size_t)r*128 + c];
                if constexpr (OUTF32)  Cf[(size_t)r*128 + c] = v;
                if constexpr (OUTBF16) Cb[(size_t)r*128 + c] = bf16u(v);
            }
        }
    }
}

// ---------------------------------------------------------------------------
// out GEMM: out = tanh( [XTb|G2b](K=256) @ W + B ); fragment LDS 64KB, 1 bar
// ---------------------------------------------------------------------------
__global__ __launch_bounds__(256)
void out_mfma(const unsigned short* __restrict__ XTb,
              const unsigned short* __restrict__ G2b,
              const unsigned short* __restrict__ WTf,
              const float* __restrict__ B, float* __restrict__ out, int nrows)
{
    __shared__ __align__(16) char lds[65536];
    char* Ar = lds;            // 32KB: A frags [4g][8ks][64ln][16B]
    char* Wr = lds + 32768;    // 32KB: B frags [4nf][8ks][64ln][16B]
    const int tid  = threadIdx.x;
    const int row0 = blockIdx.x * 64;
    const int w  = tid >> 6, ln = tid & 63, lr = ln & 15, lg = ln >> 4;
    const int lnoff = ln*16;

    #pragma unroll
    for (int i = 0; i < 8; ++i) {
        int c  = tid + i*256;                 // chunk 0..2047
        int l2 = c & 63, ks = (c>>6)&7, g = c>>9;
        int r  = g*16 + (l2 & 15);
        int k0 = ks*32 + (l2 >> 4)*8;
        uint4 v = make_uint4(0,0,0,0);
        if (row0 + r < nrows) {
            const unsigned short* src = (k0 < 128)
                ? &XTb[(size_t)(row0+r)*128 + k0]
                : &G2b[(size_t)(row0+r)*128 + (k0-128)];
            v = *(const uint4*)src;
        }
        *(uint4*)&Ar[c*16] = v;
    }
    #pragma unroll
    for (int i = 0; i < 8; ++i) {
        int c = tid + i*256;
        *(uint4*)&Wr[c*16] = *(const uint4*)&WTf[c*8];
    }
    __syncthreads();

    f32x4 acc[4];
    #pragma unroll
    for (int nf = 0; nf < 4; ++nf) acc[nf] = (f32x4){0.f,0.f,0.f,0.f};
    #pragma unroll
    for (int ks = 0; ks < 8; ++ks) {
        bfx8 a = lds_ld(&Ar[w*8192 + ks*1024 + lnoff]);
        #pragma unroll
        for (int nf = 0; nf < 4; ++nf) {
            bfx8 b = lds_ld(&Wr[(nf*8+ks)*1024 + lnoff]);
            acc[nf] = __builtin_amdgcn_mfma_f32_16x16x32_bf16(a, b, acc[nf], 0, 0, 0);
        }
    }
    #pragma unroll
    for (int nf = 0; nf < 4; ++nf) {
        float bb = B[nf*16 + lr];
        #pragma unroll
        for (int i = 0; i < 4; ++i) {
            int r = row0 + w*16 + lg*4 + i;
            if (r < nrows)
                out[(size_t)r*64 + nf*16 + lr] = tanhf(acc[nf][i] + bb);
        }
    }
}

// ---------------------------------------------------------------------------
// CSR build: histogram -> multi-block scan -> fill (packed row|val)
// ---------------------------------------------------------------------------
__global__ __launch_bounds__(256)
void edge_hist(const int* __restrict__ col, const int* __restrict__ et,
               int* __restrict__ cnt, int n, int ne)
{
    int e = blockIdx.x*256 + threadIdx.x;
    if (e >= ne) return;
    atomicAdd(&cnt[et[e]*n + col[e]], 1);
}

__global__ __launch_bounds__(1024)
void scan_block(const int* __restrict__ cnt, int* __restrict__ off,
                int* __restrict__ bsum, int n)
{
    __shared__ int s[1024];
    const int t = threadIdx.x;
    const int i = blockIdx.x*1024 + t;
    int v = (i < n) ? cnt[i] : 0;
    s[t] = v;
    __syncthreads();
    #pragma unroll
    for (int d = 1; d < 1024; d <<= 1) {
        int u = (t >= d) ? s[t-d] : 0;
        __syncthreads();
        s[t] += u;
        __syncthreads();
    }
    if (i < n) off[i] = s[t] - v;
    if (t == 1023) bsum[blockIdx.x] = s[1023];
}

__global__ __launch_bounds__(256)
void scan_bsums(int* __restrict__ bsum, int nb)
{
    __shared__ int s[256];
    const int t = threadIdx.x;
    int v = (t < nb) ? bsum[t] : 0;
    s[t] = v;
    __syncthreads();
    #pragma unroll
    for (int d = 1; d < 256; d <<= 1) {
        int u = (t >= d) ? s[t-d] : 0;
        __syncthreads();
        s[t] += u;
        __syncthreads();
    }
    if (t < nb) bsum[t] = s[t] - v;
}

__global__ __launch_bounds__(1024)
void scan_add(int* __restrict__ off, const int* __restrict__ bsum, int n)
{
    int i = blockIdx.x*1024 + threadIdx.x;
    if (i < n) off[i] += bsum[blockIdx.x];
}

__global__ __launch_bounds__(256)
void edge_fill(const int* __restrict__ row_idx, const int* __restrict__ col_idx,
               const int* __restrict__ et, const float* __restrict__ ew,
               const int* __restrict__ cnt, const int* __restrict__ off,
               int* __restrict__ cursor, uint2* __restrict__ ePack, int n, int ne)
{
    int e = blockIdx.x*256 + threadIdx.x;
    if (e >= ne) return;
    int t = et[e], c = col_idx[e], r = row_idx[e];
    int ic = t*n + c;
    int pos = atomicAdd(&cursor[ic], 1);
    int idx = off[ic] + pos;
    int p = cnt[ic] * cnt[t*n + r];
    float val = (p > 0) ? ew[e] * rsqrtf((float)p) : 0.f;
    ePack[idx] = make_uint2((unsigned)r, __builtin_bit_cast(unsigned, val));
}

// ---------------------------------------------------------------------------
// CSR gather (bf16 in, bf16 out): one wave per node, lane = 2 feature cols
// ---------------------------------------------------------------------------
__global__ __launch_bounds__(256)
void hetero_gather(const unsigned short* __restrict__ Gb,
                   const uint2* __restrict__ ePack,
                   const int* __restrict__ cnt, const int* __restrict__ off,
                   unsigned short* __restrict__ AGGb, int n)
{
    int node = blockIdx.x*4 + (threadIdx.x >> 6);
    if (node >= n) return;
    const int lane = threadIdx.x & 63;
    const int base = off[node];
    const int m = cnt[node];
    float ax = 0.f, ay = 0.f;
    int i = 0;
    for (; i + 1 < m; i += 2) {
        uint2 p0 = ePack[base+i];
        uint2 p1 = ePack[base+i+1];
        unsigned g0 = *(const unsigned*)&Gb[(size_t)p0.x*128 + lane*2];
        unsigned g1 = *(const unsigned*)&Gb[(size_t)p1.x*128 + lane*2];
        float v0 = __builtin_bit_cast(float, p0.y);
        float v1 = __builtin_bit_cast(float, p1.y);
        ax += v0*bf2f(g0 & 0xffff) + v1*bf2f(g1 & 0xffff);
        ay += v0*bf2f(g0 >> 16)    + v1*bf2f(g1 >> 16);
    }
    if (i < m) {
        uint2 p0 = ePack[base+i];
        unsigned g0 = *(const unsigned*)&Gb[(size_t)p0.x*128 + lane*2];
        float v0 = __builtin_bit_cast(float, p0.y);
        ax += v0*bf2f(g0 & 0xffff);
        ay += v0*bf2f(g0 >> 16);
    }
    unsigned pk = f2bf(ax) | (f2bf(ay) << 16);
    *(unsigned*)&AGGb[(size_t)node*128 + lane*2] = pk;
}

extern "C" void kernel_launch(void* const* d_in, const int* in_sizes, int n_in,
                              void* d_out, int out_size, void* d_ws, size_t ws_size,
                              hipStream_t stream)
{
    const float* x      = (const float*)d_in[0];
    const float* ew     = (const float*)d_in[1];
    const float* t_fc_w = (const float*)d_in[2];
    const float* t_fc_b = (const float*)d_in[3];
    const float* ln0g   = (const float*)d_in[4];
    const float* ln0b   = (const float*)d_in[5];
    const float* wvw    = (const float*)d_in[10];
    const float* wvb    = (const float*)d_in[11];
    const float* ln1g   = (const float*)d_in[12];
    const float* ln1b   = (const float*)d_in[13];
    const float* gfcw   = (const float*)d_in[14];
    const float* gfcb   = (const float*)d_in[15];
    const float* bn0g   = (const float*)d_in[16];
    const float* bn0b   = (const float*)d_in[17];
    const float* bn0m   = (const float*)d_in[18];
    const float* bn0v   = (const float*)d_in[19];
    const float* gw1    = (const float*)d_in[20];
    const float* gb1    = (const float*)d_in[21];
    const float* bn1g   = (const float*)d_in[22];
    const float* bn1b   = (const float*)d_in[23];
    const float* bn1m   = (const float*)d_in[24];
    const float* bn1v   = (const float*)d_in[25];
    const float* gw2    = (const float*)d_in[26];
    const float* gb2    = (const float*)d_in[27];
    const float* bn2g   = (const float*)d_in[28];
    const float* bn2b   = (const float*)d_in[29];
    const float* bn2m   = (const float*)d_in[30];
    const float* bn2v   = (const float*)d_in[31];
    const float* outw   = (const float*)d_in[32];
    const float* outb   = (const float*)d_in[33];
    const int*   ei     = (const int*)d_in[34];
    const int*   et     = (const int*)d_in[35];

    const int N = 100000, E = 800000;
    const size_t NF = (size_t)N*128;
    float* F1 = (float*)d_ws;                         // G1 (resid for g2)
    float* F2 = F1 + NF;                              // G  (resid for g1)
    unsigned short* B1 = (unsigned short*)(F2 + NF);  // AGG0 / AGG1
    unsigned short* B2 = B1 + NF;                     // G2b
    unsigned short* B3 = B2 + NF;                     // Gb -> G1b
    unsigned short* B4 = B3 + NF;                     // XTb
    unsigned short* WT = B4 + NF;                     // fragment-layout weights
    unsigned short* wt_tfc = WT;
    unsigned short* wt_wv  = WT + 16384;
    unsigned short* wt_gfc = WT + 2*16384;
    unsigned short* wt_g1  = WT + 3*16384;
    unsigned short* wt_g2  = WT + 4*16384;
    unsigned short* wt_out = WT + 5*16384;
    int*   cnt    = (int*)(WT + 6*16384);             // [2N]
    int*   cursor = cnt + 2*N;                        // [2N]
    int*   off    = cursor + 2*N;                     // [2N]
    uint2* ePack  = (uint2*)(off + 2*N);              // [E]
    int*   bsum   = (int*)(ePack + E);                // [256]

    dim3 blk(256);
    const int nb64 = (N + 63) / 64;
    const int* row_idx = ei;
    const int* col_idx = ei + E;
    const int nscan = 2*N;
    const int nsb = (nscan + 1023) / 1024;

    // --- CSR build ---
    hipMemsetAsync(cnt, 0, 4*(size_t)N*sizeof(int), stream);
    edge_hist<<<(E + 255)/256, blk, 0, stream>>>(col_idx, et, cnt, N, E);
    scan_block<<<nsb, 1024, 0, stream>>>(cnt, off, bsum, nscan);
    scan_bsums<<<1, 256, 0, stream>>>(bsum, nsb);
    scan_add<<<nsb, 1024, 0, stream>>>(off, bsum, nscan);
    edge_fill<<<(E + 255)/256, blk, 0, stream>>>(row_idx, col_idx, et, ew,
                                                 cnt, off, cursor, ePack, N, E);

    // --- weights -> bf16 fragment layout (single dispatch, 48 blocks) ---
    wconv_all<<<48, blk, 0, stream>>>(t_fc_w, wvw, gfcw, gw1, gw2, outw, WT);

    // --- fused front end: XTb, G(f32), Gb ---
    fused_front<<<nb64, blk, 0, stream>>>(x, wt_tfc, wt_wv, wt_gfc,
        t_fc_b, ln0g, ln0b, wvb, ln1g, ln1b,
        gfcb, bn0g, bn0b, bn0m, bn0v, B4, F2, B3, N);

    // --- GNN chain ---
    hetero_gather<<<(N + 3)/4, blk, 0, stream>>>(B3, ePack, cnt,     off,     B1, N);
    mgemm<true,true><<<nb64, blk, 0, stream>>>(B1, wt_g1, gb1, F1, B3, N,
                                               bn1g, bn1b, bn1m, bn1v, F2);
    hetero_gather<<<(N + 3)/4, blk, 0, stream>>>(B3, ePack, cnt + N, off + N, B1, N);
    mgemm<false,true><<<nb64, blk, 0, stream>>>(B1, wt_g2, gb2, nullptr, B2, N,
                                                bn2g, bn2b, bn2m, bn2v, F1);

    out_mfma<<<nb64, blk, 0, stream>>>(B4, B2, wt_out, outb, (float*)d_out, N);
}

// Round 9
// 311.514 us; speedup vs baseline: 1.4437x; 1.2309x over previous
//
#include <hip/hip_runtime.h>
#include <cmath>

#define EPSF 1e-5f

typedef __bf16 bfx8 __attribute__((ext_vector_type(8)));
typedef float  f32x4 __attribute__((ext_vector_type(4)));

__device__ __forceinline__ float4 ld4(const float* p){ return *(const float4*)p; }
__device__ __forceinline__ unsigned f2bf(float f){
    unsigned u = __builtin_bit_cast(unsigned, f);
    return (u + 0x7FFFu + ((u >> 16) & 1u)) >> 16;
}
__device__ __forceinline__ float bf2f(unsigned u){
    return __builtin_bit_cast(float, u << 16);
}
__device__ __forceinline__ bfx8 lds_ld(const char* p){ return *(const bfx8*)p; }
__device__ __forceinline__ unsigned short bf16u(float f){ return (unsigned short)f2bf(f); }

// ---------------------------------------------------------------------------
// weights -> bf16 FRAGMENT layout in global (B staging = pure linear copy):
//   seg<5 (128x128): chunk=(nf*4+ks)*64+ln, elem j = W[k][c],
//       c=nf*16+(ln&15), k=ks*32+(ln>>4)*8+j     (2048 chunks/seg)
//   seg5  (256x64):  chunk=(nf*8+ks)*64+ln, same with 64 cols, 2048 chunks.
// ---------------------------------------------------------------------------
__global__ __launch_bounds__(256)
void wconv_all(const float* __restrict__ s0, const float* __restrict__ s1,
               const float* __restrict__ s2, const float* __restrict__ s3,
               const float* __restrict__ s4, const float* __restrict__ s5,
               unsigned short* __restrict__ WT)
{
    int gid   = blockIdx.x*256 + threadIdx.x;
    int seg   = gid >> 11;
    int chunk = gid & 2047;
    int ln    = chunk & 63;
    unsigned short tmp[8];
    if (seg < 5) {
        const float* s = seg==0?s0: seg==1?s1: seg==2?s2: seg==3?s3: s4;
        int nf = chunk >> 8, ks = (chunk >> 6) & 3;
        int c  = nf*16 + (ln & 15);
        int k0 = ks*32 + (ln >> 4)*8;
        #pragma unroll
        for (int j = 0; j < 8; ++j) tmp[j] = bf16u(s[(size_t)(k0+j)*128 + c]);
        *(uint4*)&WT[seg*16384 + chunk*8] = *(uint4*)tmp;
    } else {
        int nf = chunk >> 9, ks = (chunk >> 6) & 7;
        int c  = nf*16 + (ln & 15);
        int k0 = ks*32 + (ln >> 4)*8;
        #pragma unroll
        for (int j = 0; j < 8; ++j) tmp[j] = bf16u(s5[(size_t)(k0+j)*64 + c]);
        *(uint4*)&WT[5*16384 + chunk*8] = *(uint4*)tmp;
    }
}

// ---------------------------------------------------------------------------
// fused front end, 512 threads / 8 waves, nf-split:
// wave ww: rows (ww>>1)*16..+15, output col-frags hh=ww&1 -> nf = hh*4..hh*4+3
//   H  = relu(LN(x@tfc+b)); G = relu(BN(x@gfc+b)) -> Gf,Gb
//   V = H@wv+b; XT = relu(LN(.5V+.5H)) -> XTb
//   [attention term ~1e-8, dropped: q,k normalized by GLOBAL Frobenius norm]
// LDS 51200: Ar 16K XOR A-tile | WrC 33792 (B frags 32K / f32 C-stage 64x132)
//            | LNred 1K (cross-half LN partials).  3 blocks/CU target.
// ---------------------------------------------------------------------------
__global__ __launch_bounds__(512, 6)
void fused_front(const float* __restrict__ x,
                 const unsigned short* __restrict__ wt_tfc,
                 const unsigned short* __restrict__ wt_wv,
                 const unsigned short* __restrict__ wt_gfc,
                 const float* __restrict__ tfcb, const float* __restrict__ ln0g,
                 const float* __restrict__ ln0b, const float* __restrict__ wvb,
                 const float* __restrict__ ln1g, const float* __restrict__ ln1b,
                 const float* __restrict__ gfcb, const float* __restrict__ bn0g,
                 const float* __restrict__ bn0b, const float* __restrict__ bn0m,
                 const float* __restrict__ bn0v,
                 unsigned short* __restrict__ XTb, float* __restrict__ Gf,
                 unsigned short* __restrict__ Gb, int nrows)
{
    __shared__ __align__(16) char lds[51200];
    char*   Ar    = lds;                       // 16KB XOR A-tile (x, later H)
    char*   Wr    = lds + 16384;               // 32KB B frags / 33792B Cst
    float*  Cst   = (float*)Wr;
    float2* LNred = (float2*)(lds + 50176);    // [64 rows][2 halves]
    const int tid  = threadIdx.x;
    const int row0 = blockIdx.x * 64;
    const int ww = tid >> 6, ln = tid & 63, lr = ln & 15, lg = ln >> 4;
    const int rg = ww >> 1, hh = ww & 1;
    const int ksw = (lr & 7) << 4;

    // --- stage x tile (coalesced read, XOR LDS write) ---
    #pragma unroll
    for (int i = 0; i < 2; ++i) {
        int c  = tid + i*512, r = c >> 4, k0 = (c & 15)*8;
        uint4 v4 = make_uint4(0,0,0,0);
        if (row0 + r < nrows) {
            float4 f0 = ld4(&x[(size_t)(row0+r)*128 + k0]);
            float4 f1 = ld4(&x[(size_t)(row0+r)*128 + k0 + 4]);
            v4.x = f2bf(f0.x) | (f2bf(f0.y) << 16);
            v4.y = f2bf(f0.z) | (f2bf(f0.w) << 16);
            v4.z = f2bf(f1.x) | (f2bf(f1.y) << 16);
            v4.w = f2bf(f1.z) | (f2bf(f1.w) << 16);
        }
        *(uint4*)&Ar[r*256 + ((k0*2) ^ ((r&7)<<4))] = v4;
    }
    // --- stage tfc (linear frag copy) ---
    #pragma unroll
    for (int i = 0; i < 4; ++i) {
        int c = tid + i*512;
        *(uint4*)&Wr[c*16] = *(const uint4*)&wt_tfc[c*8];
    }
    __syncthreads();                                      // (1)

    const char* Abase = &Ar[(rg*16 + lr)*256];
    f32x4 acc[4];
    float h[4][4];

    // --- GEMM1: x @ tfc (wave computes 4 nf) ---
    #pragma unroll
    for (int nf2 = 0; nf2 < 4; ++nf2) acc[nf2] = (f32x4){0.f,0.f,0.f,0.f};
    #pragma unroll
    for (int ks = 0; ks < 4; ++ks) {
        int kb = ks*64 + lg*16;
        bfx8 a = lds_ld(Abase + (kb ^ ksw));
        #pragma unroll
        for (int nf2 = 0; nf2 < 4; ++nf2) {
            bfx8 b = lds_ld(&Wr[((hh*4+nf2)*4+ks)*1024 + ln*16]);
            acc[nf2] = __builtin_amdgcn_mfma_f32_16x16x32_bf16(a, b, acc[nf2], 0, 0, 0);
        }
    }
    // --- LN0 partials ---
    #pragma unroll
    for (int nf2 = 0; nf2 < 4; ++nf2) {
        float bb = tfcb[(hh*4+nf2)*16 + lr];
        #pragma unroll
        for (int i = 0; i < 4; ++i) h[nf2][i] = acc[nf2][i] + bb;
    }
    #pragma unroll
    for (int i = 0; i < 4; ++i) {
        float s = 0.f, s2 = 0.f;
        #pragma unroll
        for (int nf2 = 0; nf2 < 4; ++nf2) { s += h[nf2][i]; s2 += h[nf2][i]*h[nf2][i]; }
        #pragma unroll
        for (int m = 1; m < 16; m <<= 1) { s += __shfl_xor(s, m); s2 += __shfl_xor(s2, m); }
        if ((ln & 15) == 0) LNred[(rg*16 + lg*4 + i)*2 + hh] = make_float2(s, s2);
    }
    __syncthreads();                                      // (2) LNred + Wr reads done
    {
        float gl[4], bl[4];
        #pragma unroll
        for (int nf2 = 0; nf2 < 4; ++nf2) {
            int c = (hh*4+nf2)*16 + lr;
            gl[nf2] = ln0g[c]; bl[nf2] = ln0b[c];
        }
        #pragma unroll
        for (int i = 0; i < 4; ++i) {
            int r = rg*16 + lg*4 + i;
            float2 p0 = LNred[r*2], p1 = LNred[r*2+1];
            float s = p0.x + p1.x, s2 = p0.y + p1.y;
            float mean = s * (1.f/128.f);
            float inv  = rsqrtf(s2 * (1.f/128.f) - mean*mean + EPSF);
            #pragma unroll
            for (int nf2 = 0; nf2 < 4; ++nf2)
                h[nf2][i] = fmaxf((h[nf2][i]-mean)*inv*gl[nf2] + bl[nf2], 0.f);
        }
    }
    // --- stage gfc ---
    #pragma unroll
    for (int i = 0; i < 4; ++i) {
        int c = tid + i*512;
        *(uint4*)&Wr[c*16] = *(const uint4*)&wt_gfc[c*8];
    }
    __syncthreads();                                      // (3)
    // --- GEMM3: x @ gfc ; BN+relu ---
    #pragma unroll
    for (int nf2 = 0; nf2 < 4; ++nf2) acc[nf2] = (f32x4){0.f,0.f,0.f,0.f};
    #pragma unroll
    for (int ks = 0; ks < 4; ++ks) {
        int kb = ks*64 + lg*16;
        bfx8 a = lds_ld(Abase + (kb ^ ksw));
        #pragma unroll
        for (int nf2 = 0; nf2 < 4; ++nf2) {
            bfx8 b = lds_ld(&Wr[((hh*4+nf2)*4+ks)*1024 + ln*16]);
            acc[nf2] = __builtin_amdgcn_mfma_f32_16x16x32_bf16(a, b, acc[nf2], 0, 0, 0);
        }
    }
    #pragma unroll
    for (int nf2 = 0; nf2 < 4; ++nf2) {
        int c = (hh*4+nf2)*16 + lr;
        float sc = bn0g[c] * rsqrtf(bn0v[c] + EPSF);
        float sh = bn0b[c] - bn0m[c]*sc;
        float bb = gfcb[c];
        #pragma unroll
        for (int i = 0; i < 4; ++i)
            acc[nf2][i] = fmaxf((acc[nf2][i] + bb)*sc + sh, 0.f);
    }
    __syncthreads();                                      // (4) Ar+Wr reads done
    // --- G -> Cst (stride 132); H -> Ar (XOR u16) ---
    #pragma unroll
    for (int nf2 = 0; nf2 < 4; ++nf2) {
        int c = (hh*4+nf2)*16 + lr;
        #pragma unroll
        for (int i = 0; i < 4; ++i) {
            int r = rg*16 + lg*4 + i;
            Cst[r*132 + c] = acc[nf2][i];
            *(unsigned short*)&Ar[(r*256 + c*2) ^ ((r&7)<<4)] = bf16u(h[nf2][i]);
        }
    }
    __syncthreads();                                      // (5)
    // --- store Gf (f32x4) + Gb (uint2), coalesced ---
    #pragma unroll
    for (int i = 0; i < 4; ++i) {
        int c = tid + i*512, r = c >> 5, k4 = (c & 31)*4;
        if (row0 + r < nrows) {
            f32x4 v = *(f32x4*)&Cst[r*132 + k4];
            *(f32x4*)&Gf[(size_t)(row0+r)*128 + k4] = v;
            uint2 pk;
            pk.x = f2bf(v[0]) | (f2bf(v[1]) << 16);
            pk.y = f2bf(v[2]) | (f2bf(v[3]) << 16);
            *(uint2*)&Gb[(size_t)(row0+r)*128 + k4] = pk;
        }
    }
    __syncthreads();                                      // (6) Cst reads done
    // --- stage wv ---
    #pragma unroll
    for (int i = 0; i < 4; ++i) {
        int c = tid + i*512;
        *(uint4*)&Wr[c*16] = *(const uint4*)&wt_wv[c*8];
    }
    __syncthreads();                                      // (7)
    // --- GEMM2: H @ wv ; 0.5V+0.5H ; LN1 partials ---
    #pragma unroll
    for (int nf2 = 0; nf2 < 4; ++nf2) acc[nf2] = (f32x4){0.f,0.f,0.f,0.f};
    #pragma unroll
    for (int ks = 0; ks < 4; ++ks) {
        int kb = ks*64 + lg*16;
        bfx8 a = lds_ld(Abase + (kb ^ ksw));
        #pragma unroll
        for (int nf2 = 0; nf2 < 4; ++nf2) {
            bfx8 b = lds_ld(&Wr[((hh*4+nf2)*4+ks)*1024 + ln*16]);
            acc[nf2] = __builtin_amdgcn_mfma_f32_16x16x32_bf16(a, b, acc[nf2], 0, 0, 0);
        }
    }
    #pragma unroll
    for (int nf2 = 0; nf2 < 4; ++nf2) {
        float bb = wvb[(hh*4+nf2)*16 + lr];
        #pragma unroll
        for (int i = 0; i < 4; ++i)
            h[nf2][i] = 0.5f*(acc[nf2][i] + bb) + 0.5f*h[nf2][i];
    }
    #pragma unroll
    for (int i = 0; i < 4; ++i) {
        float s = 0.f, s2 = 0.f;
        #pragma unroll
        for (int nf2 = 0; nf2 < 4; ++nf2) { s += h[nf2][i]; s2 += h[nf2][i]*h[nf2][i]; }
        #pragma unroll
        for (int m = 1; m < 16; m <<= 1) { s += __shfl_xor(s, m); s2 += __shfl_xor(s2, m); }
        if ((ln & 15) == 0) LNred[(rg*16 + lg*4 + i)*2 + hh] = make_float2(s, s2);
    }
    __syncthreads();                                      // (8) LNred + GEMM2 reads done
    {
        float gl[4], bl[4];
        #pragma unroll
        for (int nf2 = 0; nf2 < 4; ++nf2) {
            int c = (hh*4+nf2)*16 + lr;
            gl[nf2] = ln1g[c]; bl[nf2] = ln1b[c];
        }
        #pragma unroll
        for (int i = 0; i < 4; ++i) {
            int r = rg*16 + lg*4 + i;
            float2 p0 = LNred[r*2], p1 = LNred[r*2+1];
            float s = p0.x + p1.x, s2 = p0.y + p1.y;
            float mean = s * (1.f/128.f);
            float inv  = rsqrtf(s2 * (1.f/128.f) - mean*mean + EPSF);
            #pragma unroll
            for (int nf2 = 0; nf2 < 4; ++nf2) {
                float v = fmaxf((h[nf2][i]-mean)*inv*gl[nf2] + bl[nf2], 0.f);
                Cst[r*132 + (hh*4+nf2)*16 + lr] = v;
            }
        }
    }
    __syncthreads();                                      // (9)
    #pragma unroll
    for (int i = 0; i < 4; ++i) {
        int c = tid + i*512, r = c >> 5, k4 = (c & 31)*4;
        if (row0 + r < nrows) {
            f32x4 v = *(f32x4*)&Cst[r*132 + k4];
            uint2 pk;
            pk.x = f2bf(v[0]) | (f2bf(v[1]) << 16);
            pk.y = f2bf(v[2]) | (f2bf(v[3]) << 16);
            *(uint2*)&XTb[(size_t)(row0+r)*128 + k4] = pk;
        }
    }
}

// ---------------------------------------------------------------------------
// MFMA GEMM (GNN layers): C = BN_relu(A@W+bias) + resid. R6 structure:
// XOR A-tile (coalesced staging), linear-frag B, C-stage vector stores.
// ---------------------------------------------------------------------------
template<bool OUTF32, bool OUTBF16>
__global__ __launch_bounds__(256)
void mgemm(const unsigned short* __restrict__ Ab16, const unsigned short* __restrict__ WTf,
           const float* __restrict__ bias, float* __restrict__ Cf,
           unsigned short* __restrict__ Cb, int nrows,
           const float* __restrict__ p0, const float* __restrict__ p1,
           const float* __restrict__ p2, const float* __restrict__ p3,
           const float* __restrict__ resid)
{
    __shared__ __align__(16) char lds[50176];
    char*  Ar  = lds;            // 16KB XOR A-tile
    char*  Wr  = lds + 16384;    // 32KB B frags / 33792B Cst
    float* Cst = (float*)Wr;
    const int tid  = threadIdx.x;
    const int row0 = blockIdx.x * 64;
    const int w  = tid >> 6, ln = tid & 63, lr = ln & 15, lg = ln >> 4;
    const int ksw = (lr & 7) << 4;

    #pragma unroll
    for (int i = 0; i < 4; ++i) {
        int c  = tid + i*256, r = c >> 4, k0 = (c & 15)*8;
        uint4 v = make_uint4(0,0,0,0);
        if (row0 + r < nrows)
            v = *(const uint4*)&Ab16[(size_t)(row0+r)*128 + k0];
        *(uint4*)&Ar[r*256 + ((k0*2) ^ ((r&7)<<4))] = v;
    }
    #pragma unroll
    for (int i = 0; i < 8; ++i) {
        int c = tid + i*256;
        *(uint4*)&Wr[c*16] = *(const uint4*)&WTf[c*8];
    }
    __syncthreads();

    const char* Abase = &Ar[(w*16 + lr)*256];
    f32x4 acc[8];
    #pragma unroll
    for (int nf = 0; nf < 8; ++nf) acc[nf] = (f32x4){0.f,0.f,0.f,0.f};
    #pragma unroll
    for (int ks = 0; ks < 4; ++ks) {
        int kb = ks*64 + lg*16;
        bfx8 a = lds_ld(Abase + (kb ^ ksw));
        #pragma unroll
        for (int nf = 0; nf < 8; ++nf) {
            bfx8 b = lds_ld(&Wr[(nf*4+ks)*1024 + ln*16]);
            acc[nf] = __builtin_amdgcn_mfma_f32_16x16x32_bf16(a, b, acc[nf], 0, 0, 0);
        }
    }

    float t[8][4];
    #pragma unroll
    for (int nf = 0; nf < 8; ++nf) {
        int c = nf*16 + lr;
        float sc = p0[c] * rsqrtf(p3[c] + EPSF);
        float sh = p1[c] - p2[c]*sc;
        float bb = bias[c];
        #pragma unroll
        for (int i = 0; i < 4; ++i)
            t[nf][i] = fmaxf((acc[nf][i] + bb)*sc + sh, 0.f);
    }

    __syncthreads();
    #pragma unroll
    for (int nf = 0; nf < 8; ++nf)
        #pragma unroll
        for (int i = 0; i < 4; ++i)
            Cst[(w*16 + lg*4 + i)*132 + nf*16 + lr] = t[nf][i];
    __syncthreads();
    #pragma unroll
    for (int i = 0; i < 8; ++i) {
        int c = tid + i*256, r = c >> 5, c4 = (c & 31)*4;
        if (row0 + r >= nrows) continue;
        f32x4 v = *(f32x4*)&Cst[r*132 + c4];
        float4 rr = ld4(resid + (size_t)(row0+r)*128 + c4);
        v.x += rr.x; v.y += rr.y; v.z += rr.z; v.w += rr.w;
        if constexpr (OUTF32)
            *(f32x4*)&Cf[(size_t)(row0+r)*128 + c4] = v;
        if constexpr (OUTBF16) {
            uint2 pk;
            pk.x = f2bf(v.x) | (f2bf(v.y) << 16);
            pk.y = f2bf(v.z) | (f2bf(v.w) << 16);
            *(uint2*)&Cb[(size_t)(row0+r)*128 + c4] = pk;
        }
    }
}

// ---------------------------------------------------------------------------
// out GEMM: out = tanh( [XTb|G2b](K=256) @ W + B ); two K=128 halves,
// 32KB LDS (XOR A + linear-frag B half), 5 blocks/CU.
// ---------------------------------------------------------------------------
__global__ __launch_bounds__(256)
void out_mfma(const unsigned short* __restrict__ XTb,
              const unsigned short* __restrict__ G2b,
              const unsigned short* __restrict__ WTf,
              const float* __restrict__ B, float* __restrict__ out, int nrows)
{
    __shared__ __align__(16) char lds[32768];
    char* Ar = lds;            // 16KB XOR A half-tile
    char* Wr = lds + 16384;    // 16KB B half frags
    const int tid  = threadIdx.x;
    const int row0 = blockIdx.x * 64;
    const int w  = tid >> 6, ln = tid & 63, lr = ln & 15, lg = ln >> 4;
    const int ksw = (lr & 7) << 4;

    f32x4 acc[4];
    #pragma unroll
    for (int nf = 0; nf < 4; ++nf) acc[nf] = (f32x4){0.f,0.f,0.f,0.f};

    #pragma unroll
    for (int half = 0; half < 2; ++half) {
        const unsigned short* Asrc = half ? G2b : XTb;
        if (half) __syncthreads();
        #pragma unroll
        for (int i = 0; i < 4; ++i) {
            int c  = tid + i*256, r = c >> 4, k0 = (c & 15)*8;
            uint4 v = make_uint4(0,0,0,0);
            if (row0 + r < nrows) v = *(const uint4*)&Asrc[(size_t)(row0+r)*128 + k0];
            *(uint4*)&Ar[r*256 + ((k0*2) ^ ((r&7)<<4))] = v;
        }
        #pragma unroll
        for (int i = 0; i < 4; ++i) {
            int c = tid + i*256;                  // local chunk: nf=c>>8, ksl=(c>>6)&3, ln2=c&63
            int gidx = (((c>>8)*8) + half*4 + ((c>>6)&3))*64 + (c & 63);
            *(uint4*)&Wr[c*16] = *(const uint4*)&WTf[gidx*8];
        }
        __syncthreads();
        const char* Abase = &Ar[(w*16 + lr)*256];
        #pragma unroll
        for (int ks = 0; ks < 4; ++ks) {
            int kb = ks*64 + lg*16;
            bfx8 a = lds_ld(Abase + (kb ^ ksw));
            #pragma unroll
            for (int nf = 0; nf < 4; ++nf) {
                bfx8 b = lds_ld(&Wr[(nf*4+ks)*1024 + ln*16]);
                acc[nf] = __builtin_amdgcn_mfma_f32_16x16x32_bf16(a, b, acc[nf], 0, 0, 0);
            }
        }
    }
    #pragma unroll
    for (int nf = 0; nf < 4; ++nf) {
        float bb = B[nf*16 + lr];
        #pragma unroll
        for (int i = 0; i < 4; ++i) {
            int r = row0 + w*16 + lg*4 + i;
            if (r < nrows)
                out[(size_t)r*64 + nf*16 + lr] = tanhf(acc[nf][i] + bb);
        }
    }
}

// ---------------------------------------------------------------------------
// CSR build: histogram -> multi-block scan -> fill (packed row|val)
// ---------------------------------------------------------------------------
__global__ __launch_bounds__(256)
void edge_hist(const int* __restrict__ col, const int* __restrict__ et,
               int* __restrict__ cnt, int n, int ne)
{
    int e = blockIdx.x*256 + threadIdx.x;
    if (e >= ne) return;
    atomicAdd(&cnt[et[e]*n + col[e]], 1);
}

__global__ __launch_bounds__(1024)
void scan_block(const int* __restrict__ cnt, int* __restrict__ off,
                int* __restrict__ bsum, int n)
{
    __shared__ int s[1024];
    const int t = threadIdx.x;
    const int i = blockIdx.x*1024 + t;
    int v = (i < n) ? cnt[i] : 0;
    s[t] = v;
    __syncthreads();
    #pragma unroll
    for (int d = 1; d < 1024; d <<= 1) {
        int u = (t >= d) ? s[t-d] : 0;
        __syncthreads();
        s[t] += u;
        __syncthreads();
    }
    if (i < n) off[i] = s[t] - v;
    if (t == 1023) bsum[blockIdx.x] = s[1023];
}

__global__ __launch_bounds__(256)
void scan_bsums(int* __restrict__ bsum, int nb)
{
    __shared__ int s[256];
    const int t = threadIdx.x;
    int v = (t < nb) ? bsum[t] : 0;
    s[t] = v;
    __syncthreads();
    #pragma unroll
    for (int d = 1; d < 256; d <<= 1) {
        int u = (t >= d) ? s[t-d] : 0;
        __syncthreads();
        s[t] += u;
        __syncthreads();
    }
    if (t < nb) bsum[t] = s[t] - v;
}

__global__ __launch_bounds__(1024)
void scan_add(int* __restrict__ off, const int* __restrict__ bsum, int n)
{
    int i = blockIdx.x*1024 + threadIdx.x;
    if (i < n) off[i] += bsum[blockIdx.x];
}

__global__ __launch_bounds__(256)
void edge_fill(const int* __restrict__ row_idx, const int* __restrict__ col_idx,
               const int* __restrict__ et, const float* __restrict__ ew,
               const int* __restrict__ cnt, const int* __restrict__ off,
               int* __restrict__ cursor, uint2* __restrict__ ePack, int n, int ne)
{
    int e = blockIdx.x*256 + threadIdx.x;
    if (e >= ne) return;
    int t = et[e], c = col_idx[e], r = row_idx[e];
    int ic = t*n + c;
    int pos = atomicAdd(&cursor[ic], 1);
    int idx = off[ic] + pos;
    int p = cnt[ic] * cnt[t*n + r];
    float val = (p > 0) ? ew[e] * rsqrtf((float)p) : 0.f;
    ePack[idx] = make_uint2((unsigned)r, __builtin_bit_cast(unsigned, val));
}

// ---------------------------------------------------------------------------
// CSR gather (bf16 in, bf16 out): one wave per node, lane = 2 feature cols
// ---------------------------------------------------------------------------
__global__ __launch_bounds__(256)
void hetero_gather(const unsigned short* __restrict__ Gb,
                   const uint2* __restrict__ ePack,
                   const int* __restrict__ cnt, const int* __restrict__ off,
                   unsigned short* __restrict__ AGGb, int n)
{
    int node = blockIdx.x*4 + (threadIdx.x >> 6);
    if (node >= n) return;
    const int lane = threadIdx.x & 63;
    const int base = off[node];
    const int m = cnt[node];
    float ax = 0.f, ay = 0.f;
    int i = 0;
    for (; i + 1 < m; i += 2) {
        uint2 p0 = ePack[base+i];
        uint2 p1 = ePack[base+i+1];
        unsigned g0 = *(const unsigned*)&Gb[(size_t)p0.x*128 + lane*2];
        unsigned g1 = *(const unsigned*)&Gb[(size_t)p1.x*128 + lane*2];
        float v0 = __builtin_bit_cast(float, p0.y);
        float v1 = __builtin_bit_cast(float, p1.y);
        ax += v0*bf2f(g0 & 0xffff) + v1*bf2f(g1 & 0xffff);
        ay += v0*bf2f(g0 >> 16)    + v1*bf2f(g1 >> 16);
    }
    if (i < m) {
        uint2 p0 = ePack[base+i];
        unsigned g0 = *(const unsigned*)&Gb[(size_t)p0.x*128 + lane*2];
        float v0 = __builtin_bit_cast(float, p0.y);
        ax += v0*bf2f(g0 & 0xffff);
        ay += v0*bf2f(g0 >> 16);
    }
    unsigned pk = f2bf(ax) | (f2bf(ay) << 16);
    *(unsigned*)&AGGb[(size_t)node*128 + lane*2] = pk;
}

extern "C" void kernel_launch(void* const* d_in, const int* in_sizes, int n_in,
                              void* d_out, int out_size, void* d_ws, size_t ws_size,
                              hipStream_t stream)
{
    const float* x      = (const float*)d_in[0];
    const float* ew     = (const float*)d_in[1];
    const float* t_fc_w = (const float*)d_in[2];
    const float* t_fc_b = (const float*)d_in[3];
    const float* ln0g   = (const float*)d_in[4];
    const float* ln0b   = (const float*)d_in[5];
    const float* wvw    = (const float*)d_in[10];
    const float* wvb    = (const float*)d_in[11];
    const float* ln1g   = (const float*)d_in[12];
    const float* ln1b   = (const float*)d_in[13];
    const float* gfcw   = (const float*)d_in[14];
    const float* gfcb   = (const float*)d_in[15];
    const float* bn0g   = (const float*)d_in[16];
    const float* bn0b   = (const float*)d_in[17];
    const float* bn0m   = (const float*)d_in[18];
    const float* bn0v   = (const float*)d_in[19];
    const float* gw1    = (const float*)d_in[20];
    const float* gb1    = (const float*)d_in[21];
    const float* bn1g   = (const float*)d_in[22];
    const float* bn1b   = (const float*)d_in[23];
    const float* bn1m   = (const float*)d_in[24];
    const float* bn1v   = (const float*)d_in[25];
    const float* gw2    = (const float*)d_in[26];
    const float* gb2    = (const float*)d_in[27];
    const float* bn2g   = (const float*)d_in[28];
    const float* bn2b   = (const float*)d_in[29];
    const float* bn2m   = (const float*)d_in[30];
    const float* bn2v   = (const float*)d_in[31];
    const float* outw   = (const float*)d_in[32];
    const float* outb   = (const float*)d_in[33];
    const int*   ei     = (const int*)d_in[34];
    const int*   et     = (const int*)d_in[35];

    const int N = 100000, E = 800000;
    const size_t NF = (size_t)N*128;
    float* F1 = (float*)d_ws;                         // G1 (resid for g2)
    float* F2 = F1 + NF;                              // G  (resid for g1)
    unsigned short* B1 = (unsigned short*)(F2 + NF);  // AGG0 / AGG1
    unsigned short* B2 = B1 + NF;                     // G2b
    unsigned short* B3 = B2 + NF;                     // Gb -> G1b
    unsigned short* B4 = B3 + NF;                     // XTb
    unsigned short* WT = B4 + NF;                     // fragment-layout weights
    unsigned short* wt_tfc = WT;
    unsigned short* wt_wv  = WT + 16384;
    unsigned short* wt_gfc = WT + 2*16384;
    unsigned short* wt_g1  = WT + 3*16384;
    unsigned short* wt_g2  = WT + 4*16384;
    unsigned short* wt_out = WT + 5*16384;
    int*   cnt    = (int*)(WT + 6*16384);             // [2N]
    int*   cursor = cnt + 2*N;                        // [2N]
    int*   off    = cursor + 2*N;                     // [2N]
    uint2* ePack  = (uint2*)(off + 2*N);              // [E]
    int*   bsum   = (int*)(ePack + E);                // [256]

    dim3 blk(256), blk512(512);
    const int nb64 = (N + 63) / 64;
    const int* row_idx = ei;
    const int* col_idx = ei + E;
    const int nscan = 2*N;
    const int nsb = (nscan + 1023) / 1024;

    // --- CSR build ---
    hipMemsetAsync(cnt, 0, 4*(size_t)N*sizeof(int), stream);
    edge_hist<<<(E + 255)/256, blk, 0, stream>>>(col_idx, et, cnt, N, E);
    scan_block<<<nsb, 1024, 0, stream>>>(cnt, off, bsum, nscan);
    scan_bsums<<<1, 256, 0, stream>>>(bsum, nsb);
    scan_add<<<nsb, 1024, 0, stream>>>(off, bsum, nscan);
    edge_fill<<<(E + 255)/256, blk, 0, stream>>>(row_idx, col_idx, et, ew,
                                                 cnt, off, cursor, ePack, N, E);

    // --- weights -> bf16 fragment layout ---
    wconv_all<<<48, blk, 0, stream>>>(t_fc_w, wvw, gfcw, gw1, gw2, outw, WT);

    // --- fused front end: XTb, G(f32), Gb ---
    fused_front<<<nb64, blk512, 0, stream>>>(x, wt_tfc, wt_wv, wt_gfc,
        t_fc_b, ln0g, ln0b, wvb, ln1g, ln1b,
        gfcb, bn0g, bn0b, bn0m, bn0v, B4, F2, B3, N);

    // --- GNN chain ---
    hetero_gather<<<(N + 3)/4, blk, 0, stream>>>(B3, ePack, cnt,     off,     B1, N);
    mgemm<true,true><<<nb64, blk, 0, stream>>>(B1, wt_g1, gb1, F1, B3, N,
                                               bn1g, bn1b, bn1m, bn1v, F2);
    hetero_gather<<<(N + 3)/4, blk, 0, stream>>>(B3, ePack, cnt + N, off + N, B1, N);
    mgemm<false,true><<<nb64, blk, 0, stream>>>(B1, wt_g2, gb2, nullptr, B2, N,
                                                bn2g, bn2b, bn2m, bn2v, F1);

    out_mfma<<<nb64, blk, 0, stream>>>(B4, B2, wt_out, outb, (float*)d_out, N);
}